// Round 7
// baseline (105.178 us; speedup 1.0000x reference)
//
#include <hip/hip_runtime.h>
#include <hip/hip_bf16.h>
#include <cstdint>
#include <cstddef>
#include <cstring>

#define BN_EPS 1e-5f
#define L2E 1.4426950408889634f

typedef float f32x4_t __attribute__((ext_vector_type(4)));
typedef __bf16 bf16x8_t __attribute__((ext_vector_type(8)));

__device__ __forceinline__ unsigned short f2bf(float f) {
    __hip_bfloat16 h = __float2bfloat16(f);
    return __builtin_bit_cast(unsigned short, h);
}
__device__ __forceinline__ float bf2f(unsigned short u) {
    unsigned int v = ((unsigned int)u) << 16;
    return __builtin_bit_cast(float, v);
}
// packed bf16 pair: a -> low16, b -> high16
__device__ __forceinline__ unsigned int pkbf(float a, float b) {
    __hip_bfloat162 h = __float22bfloat162_rn(make_float2(a, b));
    unsigned int r;
    __builtin_memcpy(&r, &h, 4);
    return r;
}

// async global->LDS, 16B/lane; LDS dest is wave-uniform base + lane*16.
__device__ __forceinline__ void gld_lds16(void* lds, const void* gp) {
#if __has_builtin(__builtin_amdgcn_global_load_lds)
    __builtin_amdgcn_global_load_lds(
        (const __attribute__((address_space(1))) unsigned int*)gp,
        (__attribute__((address_space(3))) unsigned int*)lds, 16, 0, 0);
#else
    *(uint4*)lds = *(const uint4*)gp;
#endif
}

// ---------------- ws layout ----------------
// escale : float [B][T][N]                65536 f
// bns    : float sum[64]+sumsq[64]        128 f
// rowsum : float [B][N]                   8192 f
// He2    : bf16  [4 part][B*N][64]        2097152 us (4 MB)
// bmatT  : bf16  [B][512 col][N(m)]       4194304 us (8 MB)
//
// R0: G (16 MB) eliminated; A-operand exp recomputed in regs in k_gemm.
// R1: og 4->2 merge (acc[2][16], grid 512). -6.3 us.
// R2: dbuf + 3 barriers/K-step regressed (+1). REVERTED (barrier cost).
// R3: 1/rowsum folded into A-exponent; k_g+k_prep fused. -4.1 us.
// R5: triple-buffer Bs (1 barrier + counted vmcnt/K-step), log2-domain exp,
//     packed bf16. -0.7 us. Post-mortem: k_gemm is LDS-READ-bound (~1540
//     cyc/CU/K-step of ds_read_b128 vs 320 MFMA): every wave read the whole
//     B-tile (rows/wave=32 -> LDS bytes/MFMA high).
// R6 (this round): tall waves. rows/wave 32->64 (Af=4, Bf=8, acc[4][8]);
//     block 256 rows x 128 cols (8t x 16o: og(4) so the t-sum stays
//     wave-local; t == j identity). LDS reads/wave halve; exp dup x4
//     accepted (VALU ~640 < LDS saved ~770). bmatT DMA halves (rt4).
//     Triple-buffer kept: 2 DMA/thread, vmcnt(2).
// NOTE: device-scope ticket-barrier fusion cost ~20 us (prior session); keep
// k_fin/k_bn separate.

union SmemGP {
    struct {   // rowsum branch (38.9 KB)
        float praw[3072];
        float px[1024], py[1024], pz[1024], hq[1024];
        float part[16][128];
        float p2[16][32];
    } g;
    struct {   // prep branch (37.9 KB)
        unsigned short Asm[128 * 72];
        unsigned short Bsm[128 * 72];
        float sfacl[256];
    } p;
};

// K1 (fused): blocks 0..511: rowsum, 16 rows/block, XCD swizzle b=bk&7.
//             blocks 512..767: prep GEMM (independent of rowsum branch).
__global__ __launch_bounds__(256) void k_gp(const float* __restrict__ points,
                                            const float* __restrict__ trans,
                                            const float* __restrict__ funcs,
                                            const float* __restrict__ ktens,
                                            float* __restrict__ rowsum,
                                            unsigned short* __restrict__ bmatT,
                                            float* __restrict__ escale,
                                            float* __restrict__ bns) {
    __shared__ SmemGP smu;
    const int tid = threadIdx.x;

    if (blockIdx.x >= 512) {
        // ================= prep branch =================
        // bmat[m][col] = sfac[t,m] * sum_c funcs[m,c]*kt[col,c]   (NO /rowsum)
        const int bk = blockIdx.x - 512;
        const int b  = bk & 7;
        const int mt = (bk >> 3) & 7;
        const int ct = bk >> 6;            // 0..3 (t-pair)
        const int m0 = mt * 128;

        unsigned short* Asm = smu.p.Asm;   // [m][c] bf16, stride 72
        unsigned short* Bsm = smu.p.Bsm;   // [col][c] bf16, stride 72
        float* sfacl = smu.p.sfacl;        // [tloc(2)][m(128)]

        if (blockIdx.x == 512 && tid < 128) bns[tid] = 0.f;

        const int wave = tid >> 6, lane = tid & 63;
        const int wr = wave >> 1, wc = wave & 1;
        const int fr = lane & 15, quad = lane >> 4;

        // sfac + escale (global reads only; no LDS dependency)
        {
            const int tloc = tid >> 7, m = tid & 127;
            const int t = ct * 2 + tloc;
            const float tx = trans[b * 24 + t * 3], ty = trans[b * 24 + t * 3 + 1],
                        tz = trans[b * 24 + t * 3 + 2];
            const float* pp = &points[(size_t)(b * 1024 + m0 + m) * 3];
            const float ptd = pp[0] * tx + pp[1] * ty + pp[2] * tz;
            const float tsq = tx * tx + ty * ty + tz * tz;
            sfacl[tloc * 128 + m] = __expf(-ptd - 0.5f * tsq);
            escale[(size_t)(b * 8 + t) * 1024 + m0 + m] = __expf(ptd);
        }
        // stage A: funcs fp32 -> bf16 LDS [m][c]  (packed pairs)
        #pragma unroll
        for (int rep = 0; rep < 2; ++rep) {
            const int m = rep * 64 + (tid >> 2);
            const int c16 = (tid & 3) * 16;
            const float* fp = &funcs[((size_t)(b * 1024) + m0 + m) * 64 + c16];
            float4 f0 = *(const float4*)fp, f1 = *(const float4*)(fp + 4);
            float4 f2 = *(const float4*)(fp + 8), f3 = *(const float4*)(fp + 12);
            uint4 p0, p1;
            p0.x = pkbf(f0.x, f0.y); p0.y = pkbf(f0.z, f0.w);
            p0.z = pkbf(f1.x, f1.y); p0.w = pkbf(f1.z, f1.w);
            p1.x = pkbf(f2.x, f2.y); p1.y = pkbf(f2.z, f2.w);
            p1.z = pkbf(f3.x, f3.y); p1.w = pkbf(f3.z, f3.w);
            *(uint4*)&Asm[m * 72 + c16] = p0;
            *(uint4*)&Asm[m * 72 + c16 + 8] = p1;
        }
        // stage B: directly from ktens. col g = t*64+o; value[c] = ktens[(o*64+c)*8+t]
        #pragma unroll
        for (int rep = 0; rep < 4; ++rep) {
            const int col = rep * 32 + (tid >> 3);   // 0..127
            const int c8  = (tid & 7) * 8;
            const int g   = ct * 128 + col;
            const int t   = g >> 6, o = g & 63;
            const float* kt = &ktens[(size_t)(o * 64 + c8) * 8 + t];
            uint4 v;
            v.x = pkbf(kt[0], kt[8]);
            v.y = pkbf(kt[16], kt[24]);
            v.z = pkbf(kt[32], kt[40]);
            v.w = pkbf(kt[48], kt[56]);
            *(uint4*)&Bsm[col * 72 + c8] = v;
        }
        __syncthreads();

        f32x4_t acc[4][4];
        #pragma unroll
        for (int i = 0; i < 4; ++i)
            #pragma unroll
            for (int j = 0; j < 4; ++j) acc[i][j] = f32x4_t{0.f, 0.f, 0.f, 0.f};

        #pragma unroll
        for (int s = 0; s < 2; ++s) {
            uint4 afr[4], bfr[4];
            #pragma unroll
            for (int i = 0; i < 4; ++i)
                afr[i] = *(const uint4*)&Asm[(wr * 64 + i * 16 + fr) * 72 + s * 32 + quad * 8];
            #pragma unroll
            for (int j = 0; j < 4; ++j)
                bfr[j] = *(const uint4*)&Bsm[(wc * 64 + j * 16 + fr) * 72 + s * 32 + quad * 8];
            #pragma unroll
            for (int i = 0; i < 4; ++i)
                #pragma unroll
                for (int j = 0; j < 4; ++j)
                    acc[i][j] = __builtin_amdgcn_mfma_f32_16x16x32_bf16(
                        __builtin_bit_cast(bf16x8_t, afr[i]),
                        __builtin_bit_cast(bf16x8_t, bfr[j]),
                        acc[i][j], 0, 0, 0);
        }

        // epilogue: scale and pack 4 consecutive m per lane -> bmatT[b][col][m]
        #pragma unroll
        for (int i = 0; i < 4; ++i) {
            #pragma unroll
            for (int j = 0; j < 4; ++j) {
                const int colg = ct * 128 + wc * 64 + j * 16 + fr;
                const int mb = wr * 64 + i * 16 + quad * 4;
                uint2 pk;
                pk.x = pkbf(acc[i][j][0] * sfacl[wc * 128 + mb + 0],
                            acc[i][j][1] * sfacl[wc * 128 + mb + 1]);
                pk.y = pkbf(acc[i][j][2] * sfacl[wc * 128 + mb + 2],
                            acc[i][j][3] * sfacl[wc * 128 + mb + 3]);
                *(uint2*)&bmatT[(size_t)(b * 512 + colg) * 1024 + m0 + mb] = pk;
            }
        }
        return;
    }

    // ================= rowsum branch (log2-domain exp) =================
    float* praw = smu.g.praw;
    float* px = smu.g.px; float* py = smu.g.py;
    float* pz = smu.g.pz; float* hq = smu.g.hq;
    float (*part)[128] = smu.g.part;
    float (*p2)[32] = smu.g.p2;

    const int b  = blockIdx.x & 7;               // XCD swizzle
    const int n0 = (blockIdx.x >> 3) * 16;

    for (int i = tid; i < 3072; i += 256) praw[i] = points[b * 3072 + i];
    __syncthreads();
    for (int n = tid; n < 1024; n += 256) {
        float x = praw[n * 3], y = praw[n * 3 + 1], z = praw[n * 3 + 2];
        px[n] = x; py[n] = y; pz[n] = z;
        hq[n] = -0.5f * L2E * (x * x + y * y + z * z);   // log2-scaled
    }
    __syncthreads();

    const int rhalf = tid >> 7;                  // 0/1: which row of the pair
    const int c0 = (tid & 127) * 8;              // column octet
    float vx[8], vy[8], vz[8], vh[8];
    *(float4*)&vx[0] = *(const float4*)&px[c0];
    *(float4*)&vx[4] = *(const float4*)&px[c0 + 4];
    *(float4*)&vy[0] = *(const float4*)&py[c0];
    *(float4*)&vy[4] = *(const float4*)&py[c0 + 4];
    *(float4*)&vz[0] = *(const float4*)&pz[c0];
    *(float4*)&vz[4] = *(const float4*)&pz[c0 + 4];
    *(float4*)&vh[0] = *(const float4*)&hq[c0];
    *(float4*)&vh[4] = *(const float4*)&hq[c0 + 4];

    #pragma unroll
    for (int u = 0; u < 8; ++u) {
        const int rl = u * 2 + rhalf;            // 0..15
        const int row = n0 + rl;
        const float rx = L2E * px[row], ry = L2E * py[row], rz = L2E * pz[row];
        const float hr = hq[row];
        float ssum = 0.f;
        #pragma unroll
        for (int j = 0; j < 8; ++j)
            ssum += __builtin_amdgcn_exp2f(hr + vh[j] + rx * vx[j]
                                           + ry * vy[j] + rz * vz[j]);
        part[rl][tid & 127] = ssum;
    }
    __syncthreads();
    #pragma unroll
    for (int rep = 0; rep < 2; ++rep) {   // level 1: 128 -> 32 partials per row
        const int row = rep * 8 + (tid >> 5), c4l = (tid & 31) * 4;
        float4 p = *(const float4*)&part[row][c4l];
        p2[row][tid & 31] = p.x + p.y + p.z + p.w;
    }
    __syncthreads();
    if (tid < 16) {   // level 2: 16 thr finish their row
        float s = 0.f;
        #pragma unroll
        for (int q = 0; q < 8; ++q) {
            float4 v = *(const float4*)&p2[tid][q * 4];
            s += v.x + v.y + v.z + v.w;
        }
        rowsum[b * 1024 + n0 + tid] = s;
    }
}

// K3 (R6): FUSED Gaussian + bf16 GEMM, tall waves. grid 512 = b8 x rt4 x og4
// x kh4; 4 waves; block 256 rows x 128 cols (c' = t*16 + o, t==j identity).
// Wave = 64 rows x 128 cols: Af=4 A-frags (computed exps), Bf=8 B-frags from
// LDS -> LDS reads/MFMA halved vs R5 (was the binding pipe). Triple-buffered
// Bs (8 KB/buf), 2 DMA/thread/K-step, counted vmcnt(2), one barrier/K-step.
__global__ __launch_bounds__(256, 2) void k_gemm(const float* __restrict__ points,
                                                 const unsigned short* __restrict__ bmatT,
                                                 const float* __restrict__ escale,
                                                 const float* __restrict__ rowsum,
                                                 unsigned short* __restrict__ He2) {
    __shared__ unsigned short Bs[3][4096];  // 3 x [c'(128)=t*16+o][k(32)], k-swizzled
    __shared__ float escT[2048];            // [t(8)][row(256)]
    __shared__ float4 mp[256];              // m-points: x,y,z, L2E*hq - log2(rowsum)

    const int b  = blockIdx.x & 7;          // XCD swizzle
    const int rt = (blockIdx.x >> 3) & 3;
    const int og = (blockIdx.x >> 5) & 3;   // 16-channel group
    const int kh = blockIdx.x >> 7;         // 0..3 K quarter
    const int n0 = rt * 256;
    const int kb = kh * 256;

    const int tid  = threadIdx.x;
    const int wave = tid >> 6, lane = tid & 63;

    const unsigned short* gB = bmatT + (size_t)(b * 512 + og * 16) * 1024 + kb;

    const int r16 = lane >> 2;            // o within t-seg (stage side)
    const int kq  = lane & 3;             // dest 16B k-group
    const int gsw = kq ^ (r16 & 3);       // swizzled source k-group

    const int fr = lane & 15;             // fragment row/col part
    const int quad = lane >> 4;           // fragment k part
    const int swoff = (quad ^ (fr & 3)) << 4;   // swizzled frag byte offset
    const int row_base = wave * 64;       // this wave's 64 output rows

    // 4 fixed A-rows per lane, log2-scaled
    float rx[4], ry[4], rz[4], rh[4];
    #pragma unroll
    for (int i = 0; i < 4; ++i) {
        const float* p = &points[(size_t)(b * 1024 + n0 + row_base + i * 16 + fr) * 3];
        const float x = p[0], y = p[1], z = p[2];
        rh[i] = -0.5f * L2E * (x * x + y * y + z * z);
        rx[i] = L2E * x; ry[i] = L2E * y; rz[i] = L2E * z;
    }
    // escT: 8t x 256 rows (2 reps of 128)
    #pragma unroll
    for (int rep = 0; rep < 2; ++rep) {
        const int t = tid >> 5, r4 = rep * 128 + (tid & 31) * 4;
        *(float4*)&escT[t * 256 + r4] =
            *(const float4*)&escale[(size_t)(b * 8 + t) * 1024 + n0 + r4];
    }
    {   // stage the 256 m-points: (x,y,z, L2E*hq - log2 rowsum)
        const float* pp = &points[(size_t)(b * 1024 + kb + tid) * 3];
        const float x = pp[0], y = pp[1], zz = pp[2];
        const float rs = rowsum[b * 1024 + kb + tid];
        mp[tid] = make_float4(x, y, zz,
                              -0.5f * L2E * (x * x + y * y + zz * zz)
                              - __builtin_amdgcn_logf(rs));
    }
    __builtin_amdgcn_sched_barrier(0);
    #pragma unroll
    for (int i = 0; i < 2; ++i) {         // W(0) into Bs[0]; seg == t
        const int seg = wave * 2 + i;
        gld_lds16((char*)Bs[0] + seg * 1024 + lane * 16,
                  gB + (size_t)(seg * 64 + r16) * 1024 + gsw * 8);
    }
    asm volatile("s_waitcnt lgkmcnt(0)" ::: "memory");  // publish escT/mp only
    __builtin_amdgcn_s_barrier();

    f32x4_t acc[4][8];
    #pragma unroll
    for (int i = 0; i < 4; ++i)
        #pragma unroll
        for (int j = 0; j < 8; ++j) acc[i][j] = f32x4_t{0.f, 0.f, 0.f, 0.f};

    #pragma unroll
    for (int kk = 0; kk < 8; ++kk) {
        const int cur = kk % 3;
        if (kk < 7) {                     // W(k+1) into Bs[(k+1)%3]
            const int nxt = (kk + 1) % 3;
            const int k0n = (kk + 1) * 32;
            #pragma unroll
            for (int i = 0; i < 2; ++i) {
                const int seg = wave * 2 + i;
                gld_lds16((char*)Bs[nxt] + seg * 1024 + lane * 16,
                          gB + (size_t)(seg * 64 + r16) * 1024 + k0n + gsw * 8);
            }
        }
        // A fragments: 4 rows x 8 m exps (log2 domain), packed bf16
        uint4 afr[4];
        {
            const int mbase = kk * 32 + quad * 8;
            float e[4][8];
            #pragma unroll
            for (int j = 0; j < 8; ++j) {
                const float4 m4 = mp[mbase + j];
                #pragma unroll
                for (int i = 0; i < 4; ++i)
                    e[i][j] = __builtin_amdgcn_exp2f(rh[i] + m4.w + rx[i] * m4.x
                                                     + ry[i] * m4.y + rz[i] * m4.z);
            }
            #pragma unroll
            for (int i = 0; i < 4; ++i) {
                afr[i].x = pkbf(e[i][0], e[i][1]);
                afr[i].y = pkbf(e[i][2], e[i][3]);
                afr[i].z = pkbf(e[i][4], e[i][5]);
                afr[i].w = pkbf(e[i][6], e[i][7]);
            }
        }
        // counted drain: wait only W(k)'s 2 (oldest); W(k+1) stays in flight.
        if (kk < 7) asm volatile("s_waitcnt vmcnt(2)" ::: "memory");
        else        asm volatile("s_waitcnt vmcnt(0)" ::: "memory");
        __builtin_amdgcn_s_barrier();
        #pragma unroll
        for (int j = 0; j < 8; ++j) {     // one B-frag serves 4 MFMAs
            uint4 bfr = *(const uint4*)((const char*)Bs[cur] + (j * 16 + fr) * 64 + swoff);
            #pragma unroll
            for (int i = 0; i < 4; ++i)
                acc[i][j] = __builtin_amdgcn_mfma_f32_16x16x32_bf16(
                    __builtin_bit_cast(bf16x8_t, afr[i]),
                    __builtin_bit_cast(bf16x8_t, bfr), acc[i][j], 0, 0, 0);
        }
    }

    // epilogue: res[row][ch] = sum_t escT[t][row] * acc[i][t]  (t == j).
    // Lane's channel = og*16 + fr; rows = row_base + i*16 + quad*4 + r.
    unsigned short* dst = He2 + (size_t)kh * 524288
                              + (size_t)(b * 1024 + n0) * 64 + og * 16 + fr;
    #pragma unroll
    for (int i = 0; i < 4; ++i) {
        const int rb = row_base + i * 16 + quad * 4;
        float s[4] = {0.f, 0.f, 0.f, 0.f};
        #pragma unroll
        for (int t = 0; t < 8; ++t) {
            const float4 ev = *(const float4*)&escT[t * 256 + rb];
            s[0] += ev.x * acc[i][t][0];
            s[1] += ev.y * acc[i][t][1];
            s[2] += ev.z * acc[i][t][2];
            s[3] += ev.w * acc[i][t][3];
        }
        #pragma unroll
        for (int r = 0; r < 4; ++r)
            dst[(size_t)(rb + r) * 64] = f2bf(s[r]);
    }
}

// K4: out = sum of 4 bf16 He2 partials; fused BN sum/sumsq.
// XCD-matched remap: data-b == blockIdx&7 == XCD (same swizzle as producers).
__global__ __launch_bounds__(256) void k_fin(const unsigned short* __restrict__ He2,
                                             float* __restrict__ out,
                                             float* __restrict__ bns) {
    __shared__ float s1[16][64], s2[16][64];
    const int tid = threadIdx.x;
    const int vb = ((blockIdx.x & 7) << 5) | (blockIdx.x >> 3);  // bijective
    float a0 = 0.f, a1 = 0.f, a2 = 0.f, a3 = 0.f;
    float q0 = 0.f, q1 = 0.f, q2 = 0.f, q3 = 0.f;
    #pragma unroll
    for (int it = 0; it < 2; ++it) {
        const size_t idx = (size_t)vb * 512 + it * 256 + tid;    // ushort4 group
        float4 s = make_float4(0.f, 0.f, 0.f, 0.f);
        #pragma unroll
        for (int p = 0; p < 4; ++p) {
            ushort4 u = *(const ushort4*)(He2 + (size_t)p * 524288 + idx * 4);
            s.x += bf2f(u.x); s.y += bf2f(u.y); s.z += bf2f(u.z); s.w += bf2f(u.w);
        }
        ((float4*)out)[idx] = s;
        a0 += s.x; a1 += s.y; a2 += s.z; a3 += s.w;
        q0 += s.x * s.x; q1 += s.y * s.y; q2 += s.z * s.z; q3 += s.w * s.w;
    }
    const int g = tid >> 4, o4 = (tid & 15) * 4;
    *(float4*)&s1[g][o4] = make_float4(a0, a1, a2, a3);
    *(float4*)&s2[g][o4] = make_float4(q0, q1, q2, q3);
    __syncthreads();
    if (tid < 64) {
        float sa = 0.f, sb = 0.f;
        #pragma unroll
        for (int r = 0; r < 16; ++r) { sa += s1[r][tid]; sb += s2[r][tid]; }
        atomicAdd(&bns[tid], sa);
        atomicAdd(&bns[64 + tid], sb);
    }
}

// K5: in-place BN (training stats) + ReLU. XCD-matched remap like k_fin.
__global__ __launch_bounds__(256) void k_bn(float* __restrict__ out,
                                            const float* __restrict__ bns,
                                            const float* __restrict__ gamma,
                                            const float* __restrict__ beta) {
    const int vb = ((blockIdx.x & 7) << 6) | (blockIdx.x >> 3);  // bijective
    const int i = vb * 256 + threadIdx.x;
    const int o4 = (i & 15) * 4;
    float4 x = ((float4*)out)[i];
    const float4 s  = *(const float4*)&bns[o4];
    const float4 s2 = *(const float4*)&bns[64 + o4];
    const float4 gm = *(const float4*)&gamma[o4];
    const float4 bt = *(const float4*)&beta[o4];
    const float invn = 1.f / 8192.f;
    float m, v, w;
    m = s.x * invn; v = s2.x * invn - m * m; w = __frsqrt_rn(v + BN_EPS) * gm.x;
    x.x = fmaxf((x.x - m) * w + bt.x, 0.f);
    m = s.y * invn; v = s2.y * invn - m * m; w = __frsqrt_rn(v + BN_EPS) * gm.y;
    x.y = fmaxf((x.y - m) * w + bt.y, 0.f);
    m = s.z * invn; v = s2.z * invn - m * m; w = __frsqrt_rn(v + BN_EPS) * gm.z;
    x.z = fmaxf((x.z - m) * w + bt.z, 0.f);
    m = s.w * invn; v = s2.w * invn - m * m; w = __frsqrt_rn(v + BN_EPS) * gm.w;
    x.w = fmaxf((x.w - m) * w + bt.w, 0.f);
    ((float4*)out)[i] = x;
}

extern "C" void kernel_launch(void* const* d_in, const int* in_sizes, int n_in,
                              void* d_out, int out_size, void* d_ws, size_t ws_size,
                              hipStream_t stream) {
    const float* points = (const float*)d_in[0];
    const float* trans  = (const float*)d_in[1];
    const float* funcs  = (const float*)d_in[2];
    const float* ktens  = (const float*)d_in[3];
    const float* gamma  = (const float*)d_in[4];
    const float* beta   = (const float*)d_in[5];
    float* out = (float*)d_out;

    float* ws      = (float*)d_ws;
    float* escale  = ws;                    // 65536 f
    float* bns     = escale + 65536;        // 128 f
    float* rowsum  = bns + 128;             // 8192 f
    unsigned short* He2   = (unsigned short*)(rowsum + 8192);   // 2097152 us (4 MB)
    unsigned short* bmatT = He2 + 2097152;                      // 4194304 us (8 MB)

    k_gp<<<768, 256, 0, stream>>>(points, trans, funcs, ktens,
                                  rowsum, bmatT, escale, bns);
    k_gemm<<<512, 256, 0, stream>>>(points, bmatT, escale, rowsum, He2);
    k_fin<<<256, 256, 0, stream>>>(He2, out, bns);
    k_bn<<<512, 256, 0, stream>>>(out, bns, gamma, beta);
}

// Round 8
// 102.843 us; speedup vs baseline: 1.0227x; 1.0227x over previous
//
#include <hip/hip_runtime.h>
#include <hip/hip_bf16.h>
#include <cstdint>
#include <cstddef>
#include <cstring>

#define BN_EPS 1e-5f
#define L2E 1.4426950408889634f

typedef float f32x4_t __attribute__((ext_vector_type(4)));
typedef __bf16 bf16x8_t __attribute__((ext_vector_type(8)));

__device__ __forceinline__ unsigned short f2bf(float f) {
    __hip_bfloat16 h = __float2bfloat16(f);
    return __builtin_bit_cast(unsigned short, h);
}
__device__ __forceinline__ float bf2f(unsigned short u) {
    unsigned int v = ((unsigned int)u) << 16;
    return __builtin_bit_cast(float, v);
}
// packed bf16 pair: a -> low16, b -> high16
__device__ __forceinline__ unsigned int pkbf(float a, float b) {
    __hip_bfloat162 h = __float22bfloat162_rn(make_float2(a, b));
    unsigned int r;
    __builtin_memcpy(&r, &h, 4);
    return r;
}

// async global->LDS, 16B/lane; LDS dest is wave-uniform base + lane*16.
__device__ __forceinline__ void gld_lds16(void* lds, const void* gp) {
#if __has_builtin(__builtin_amdgcn_global_load_lds)
    __builtin_amdgcn_global_load_lds(
        (const __attribute__((address_space(1))) unsigned int*)gp,
        (__attribute__((address_space(3))) unsigned int*)lds, 16, 0, 0);
#else
    *(uint4*)lds = *(const uint4*)gp;
#endif
}

// ---------------- ws layout ----------------
// escale : float [B][T][N]                65536 f
// bns    : float sum[64]+sumsq[64]        128 f
// rowsum : float [B][N]                   8192 f
// He2    : bf16  [4 part][B*N][64]        2097152 us (4 MB)
// bmatT  : bf16  [B][512 col][N(m)]       4194304 us (8 MB)
//
// R0: G (16 MB) eliminated; A-operand exp recomputed in regs in k_gemm.
// R1: og 4->2 merge (acc[2][16], grid 512). -6.3 us.
// R2: dbuf + 3 barriers/K-step regressed (+1). REVERTED (barrier cost).
// R3: 1/rowsum folded into A-exponent; k_g+k_prep fused. -4.1 us.
// R5: triple-buffer Bs (1 barrier + counted vmcnt/K-step), log2-domain exp,
//     packed bf16. -0.7 us -> 102.4 (best).
// R6: tall waves (acc[4][8], og4) regressed +2.8 us -- model said LDS-bound
//     but register pressure (spills/alloc under launch_bounds(256,2)) ate it.
//     REVERTED. Lesson: acc[2][16] + compiler schedule is the sweet spot;
//     both axes away from it (R2/R6) lose.
// R7: pure revert to the R5-measured k_gemm. No new experiment.
// NOTE: device-scope ticket-barrier fusion cost ~20 us (prior session); keep
// k_fin/k_bn separate. BK=64 / fat-acc cross the VGPR cliff; keep BK=32.

union SmemGP {
    struct {   // rowsum branch (38.9 KB)
        float praw[3072];
        float px[1024], py[1024], pz[1024], hq[1024];
        float part[16][128];
        float p2[16][32];
    } g;
    struct {   // prep branch (37.9 KB)
        unsigned short Asm[128 * 72];
        unsigned short Bsm[128 * 72];
        float sfacl[256];
    } p;
};

// K1 (fused): blocks 0..511: rowsum, 16 rows/block, XCD swizzle b=bk&7.
//             blocks 512..767: prep GEMM (independent of rowsum branch).
__global__ __launch_bounds__(256) void k_gp(const float* __restrict__ points,
                                            const float* __restrict__ trans,
                                            const float* __restrict__ funcs,
                                            const float* __restrict__ ktens,
                                            float* __restrict__ rowsum,
                                            unsigned short* __restrict__ bmatT,
                                            float* __restrict__ escale,
                                            float* __restrict__ bns) {
    __shared__ SmemGP smu;
    const int tid = threadIdx.x;

    if (blockIdx.x >= 512) {
        // ================= prep branch =================
        // bmat[m][col] = sfac[t,m] * sum_c funcs[m,c]*kt[col,c]   (NO /rowsum)
        const int bk = blockIdx.x - 512;
        const int b  = bk & 7;
        const int mt = (bk >> 3) & 7;
        const int ct = bk >> 6;            // 0..3 (t-pair)
        const int m0 = mt * 128;

        unsigned short* Asm = smu.p.Asm;   // [m][c] bf16, stride 72
        unsigned short* Bsm = smu.p.Bsm;   // [col][c] bf16, stride 72
        float* sfacl = smu.p.sfacl;        // [tloc(2)][m(128)]

        if (blockIdx.x == 512 && tid < 128) bns[tid] = 0.f;

        const int wave = tid >> 6, lane = tid & 63;
        const int wr = wave >> 1, wc = wave & 1;
        const int fr = lane & 15, quad = lane >> 4;

        // sfac + escale (global reads only; no LDS dependency)
        {
            const int tloc = tid >> 7, m = tid & 127;
            const int t = ct * 2 + tloc;
            const float tx = trans[b * 24 + t * 3], ty = trans[b * 24 + t * 3 + 1],
                        tz = trans[b * 24 + t * 3 + 2];
            const float* pp = &points[(size_t)(b * 1024 + m0 + m) * 3];
            const float ptd = pp[0] * tx + pp[1] * ty + pp[2] * tz;
            const float tsq = tx * tx + ty * ty + tz * tz;
            sfacl[tloc * 128 + m] = __expf(-ptd - 0.5f * tsq);
            escale[(size_t)(b * 8 + t) * 1024 + m0 + m] = __expf(ptd);
        }
        // stage A: funcs fp32 -> bf16 LDS [m][c]  (packed pairs)
        #pragma unroll
        for (int rep = 0; rep < 2; ++rep) {
            const int m = rep * 64 + (tid >> 2);
            const int c16 = (tid & 3) * 16;
            const float* fp = &funcs[((size_t)(b * 1024) + m0 + m) * 64 + c16];
            float4 f0 = *(const float4*)fp, f1 = *(const float4*)(fp + 4);
            float4 f2 = *(const float4*)(fp + 8), f3 = *(const float4*)(fp + 12);
            uint4 p0, p1;
            p0.x = pkbf(f0.x, f0.y); p0.y = pkbf(f0.z, f0.w);
            p0.z = pkbf(f1.x, f1.y); p0.w = pkbf(f1.z, f1.w);
            p1.x = pkbf(f2.x, f2.y); p1.y = pkbf(f2.z, f2.w);
            p1.z = pkbf(f3.x, f3.y); p1.w = pkbf(f3.z, f3.w);
            *(uint4*)&Asm[m * 72 + c16] = p0;
            *(uint4*)&Asm[m * 72 + c16 + 8] = p1;
        }
        // stage B: directly from ktens. col g = t*64+o; value[c] = ktens[(o*64+c)*8+t]
        #pragma unroll
        for (int rep = 0; rep < 4; ++rep) {
            const int col = rep * 32 + (tid >> 3);   // 0..127
            const int c8  = (tid & 7) * 8;
            const int g   = ct * 128 + col;
            const int t   = g >> 6, o = g & 63;
            const float* kt = &ktens[(size_t)(o * 64 + c8) * 8 + t];
            uint4 v;
            v.x = pkbf(kt[0], kt[8]);
            v.y = pkbf(kt[16], kt[24]);
            v.z = pkbf(kt[32], kt[40]);
            v.w = pkbf(kt[48], kt[56]);
            *(uint4*)&Bsm[col * 72 + c8] = v;
        }
        __syncthreads();

        f32x4_t acc[4][4];
        #pragma unroll
        for (int i = 0; i < 4; ++i)
            #pragma unroll
            for (int j = 0; j < 4; ++j) acc[i][j] = f32x4_t{0.f, 0.f, 0.f, 0.f};

        #pragma unroll
        for (int s = 0; s < 2; ++s) {
            uint4 afr[4], bfr[4];
            #pragma unroll
            for (int i = 0; i < 4; ++i)
                afr[i] = *(const uint4*)&Asm[(wr * 64 + i * 16 + fr) * 72 + s * 32 + quad * 8];
            #pragma unroll
            for (int j = 0; j < 4; ++j)
                bfr[j] = *(const uint4*)&Bsm[(wc * 64 + j * 16 + fr) * 72 + s * 32 + quad * 8];
            #pragma unroll
            for (int i = 0; i < 4; ++i)
                #pragma unroll
                for (int j = 0; j < 4; ++j)
                    acc[i][j] = __builtin_amdgcn_mfma_f32_16x16x32_bf16(
                        __builtin_bit_cast(bf16x8_t, afr[i]),
                        __builtin_bit_cast(bf16x8_t, bfr[j]),
                        acc[i][j], 0, 0, 0);
        }

        // epilogue: scale and pack 4 consecutive m per lane -> bmatT[b][col][m]
        #pragma unroll
        for (int i = 0; i < 4; ++i) {
            #pragma unroll
            for (int j = 0; j < 4; ++j) {
                const int colg = ct * 128 + wc * 64 + j * 16 + fr;
                const int mb = wr * 64 + i * 16 + quad * 4;
                uint2 pk;
                pk.x = pkbf(acc[i][j][0] * sfacl[wc * 128 + mb + 0],
                            acc[i][j][1] * sfacl[wc * 128 + mb + 1]);
                pk.y = pkbf(acc[i][j][2] * sfacl[wc * 128 + mb + 2],
                            acc[i][j][3] * sfacl[wc * 128 + mb + 3]);
                *(uint2*)&bmatT[(size_t)(b * 512 + colg) * 1024 + m0 + mb] = pk;
            }
        }
        return;
    }

    // ================= rowsum branch (log2-domain exp) =================
    float* praw = smu.g.praw;
    float* px = smu.g.px; float* py = smu.g.py;
    float* pz = smu.g.pz; float* hq = smu.g.hq;
    float (*part)[128] = smu.g.part;
    float (*p2)[32] = smu.g.p2;

    const int b  = blockIdx.x & 7;               // XCD swizzle
    const int n0 = (blockIdx.x >> 3) * 16;

    for (int i = tid; i < 3072; i += 256) praw[i] = points[b * 3072 + i];
    __syncthreads();
    for (int n = tid; n < 1024; n += 256) {
        float x = praw[n * 3], y = praw[n * 3 + 1], z = praw[n * 3 + 2];
        px[n] = x; py[n] = y; pz[n] = z;
        hq[n] = -0.5f * L2E * (x * x + y * y + z * z);   // log2-scaled
    }
    __syncthreads();

    const int rhalf = tid >> 7;                  // 0/1: which row of the pair
    const int c0 = (tid & 127) * 8;              // column octet
    float vx[8], vy[8], vz[8], vh[8];
    *(float4*)&vx[0] = *(const float4*)&px[c0];
    *(float4*)&vx[4] = *(const float4*)&px[c0 + 4];
    *(float4*)&vy[0] = *(const float4*)&py[c0];
    *(float4*)&vy[4] = *(const float4*)&py[c0 + 4];
    *(float4*)&vz[0] = *(const float4*)&pz[c0];
    *(float4*)&vz[4] = *(const float4*)&pz[c0 + 4];
    *(float4*)&vh[0] = *(const float4*)&hq[c0];
    *(float4*)&vh[4] = *(const float4*)&hq[c0 + 4];

    #pragma unroll
    for (int u = 0; u < 8; ++u) {
        const int rl = u * 2 + rhalf;            // 0..15
        const int row = n0 + rl;
        const float rx = L2E * px[row], ry = L2E * py[row], rz = L2E * pz[row];
        const float hr = hq[row];
        float ssum = 0.f;
        #pragma unroll
        for (int j = 0; j < 8; ++j)
            ssum += __builtin_amdgcn_exp2f(hr + vh[j] + rx * vx[j]
                                           + ry * vy[j] + rz * vz[j]);
        part[rl][tid & 127] = ssum;
    }
    __syncthreads();
    #pragma unroll
    for (int rep = 0; rep < 2; ++rep) {   // level 1: 128 -> 32 partials per row
        const int row = rep * 8 + (tid >> 5), c4l = (tid & 31) * 4;
        float4 p = *(const float4*)&part[row][c4l];
        p2[row][tid & 31] = p.x + p.y + p.z + p.w;
    }
    __syncthreads();
    if (tid < 16) {   // level 2: 16 thr finish their row
        float s = 0.f;
        #pragma unroll
        for (int q = 0; q < 8; ++q) {
            float4 v = *(const float4*)&p2[tid][q * 4];
            s += v.x + v.y + v.z + v.w;
        }
        rowsum[b * 1024 + n0 + tid] = s;
    }
}

// K3 (R5 form, measured 102.4): FUSED Gaussian + bf16 GEMM, BK=32, og-pair
// merged, TRIPLE-buffered Bs, one s_barrier + counted vmcnt per K-step.
// Hazards: iter k = [W((k+1)%3); A-exp; vmcnt(4); BAR; R(k%3)]. In any barrier
// interval, concurrent W/R buffer indices differ by 2 mod 3 -> disjoint.
// vmcnt: outstanding = W(k)4 + W(k+1)4 = 8 -> vmcnt(4) drains exactly W(k).
// grid 512 = b(8) x rt(8) x [ogp(2) x kh(4)]; 4 waves; 128 rows x 256 cols.
__global__ __launch_bounds__(256, 2) void k_gemm(const float* __restrict__ points,
                                                 const unsigned short* __restrict__ bmatT,
                                                 const float* __restrict__ escale,
                                                 const float* __restrict__ rowsum,
                                                 unsigned short* __restrict__ He2) {
    __shared__ unsigned short Bs[3][8192];  // 3 x [c'(256)=t*32+oo][k(32)], k-swizzled
    __shared__ float escT[1024];            // [t(8)][row(128)]
    __shared__ float4 mp[256];              // m-points: x,y,z, L2E*hq - log2(rowsum)

    const int b  = blockIdx.x & 7;        // XCD swizzle
    const int rt = (blockIdx.x >> 3) & 7;
    const int z  = blockIdx.x >> 6;       // 0..7
    const int ogp = z & 1;                // channel half (32 ch)
    const int kh  = z >> 1;               // K quarter
    const int n0 = rt * 128;
    const int kb = kh * 256;

    const int tid  = threadIdx.x;
    const int wave = tid >> 6, lane = tid & 63;

    const unsigned short* gB = bmatT + (size_t)(b * 512 + ogp * 32) * 1024 + kb;

    const int r16 = lane >> 2;            // row within 16-seg
    const int kq  = lane & 3;             // dest 16B k-group
    const int gsw = kq ^ (r16 & 3);       // swizzled source k-group

    const int fr = lane & 15;             // fragment row part
    const int quad = lane >> 4;           // fragment k part
    const int swoff = (quad ^ (fr & 3)) << 4;   // swizzled frag byte offset
    const int row_base = wave * 32;       // this wave's 32 output rows

    // row registers: this lane's 2 fixed A-rows, log2-scaled
    float rx0, ry0, rz0, rh0, rx1, ry1, rz1, rh1;
    {
        const float* p0 = &points[(size_t)(b * 1024 + n0 + row_base + fr) * 3];
        const float x0 = p0[0], y0 = p0[1], z0 = p0[2];
        rh0 = -0.5f * L2E * (x0 * x0 + y0 * y0 + z0 * z0);
        rx0 = L2E * x0; ry0 = L2E * y0; rz0 = L2E * z0;
        const float* p1 = &points[(size_t)(b * 1024 + n0 + row_base + 16 + fr) * 3];
        const float x1 = p1[0], y1 = p1[1], z1 = p1[2];
        rh1 = -0.5f * L2E * (x1 * x1 + y1 * y1 + z1 * z1);
        rx1 = L2E * x1; ry1 = L2E * y1; rz1 = L2E * z1;
    }
    {   // stage escale [8t][128 rows] + m-points (x,y,z, L2E*hq - log2 rs)
        const int t = tid >> 5, r4 = (tid & 31) * 4;
        float4 ev = *(const float4*)&escale[(size_t)(b * 8 + t) * 1024 + n0 + r4];
        const float* pp = &points[(size_t)(b * 1024 + kb + tid) * 3];
        const float x = pp[0], y = pp[1], zz = pp[2];
        const float rs = rowsum[b * 1024 + kb + tid];
        *(float4*)&escT[t * 128 + r4] = ev;
        mp[tid] = make_float4(x, y, zz,
                              -0.5f * L2E * (x * x + y * y + zz * zz)
                              - __builtin_amdgcn_logf(rs));
    }
    __builtin_amdgcn_sched_barrier(0);
    #pragma unroll
    for (int i = 0; i < 4; ++i) {         // W(0) into Bs[0]
        const int seg = wave * 4 + i;
        const int tt = seg >> 1, oh = (seg & 1) * 16;
        gld_lds16((char*)Bs[0] + seg * 1024 + lane * 16,
                  gB + (size_t)(tt * 64 + oh + r16) * 1024 + gsw * 8);
    }
    asm volatile("s_waitcnt lgkmcnt(0)" ::: "memory");  // publish escT/mp only
    __builtin_amdgcn_s_barrier();

    f32x4_t acc[2][16];
    #pragma unroll
    for (int i = 0; i < 2; ++i)
        #pragma unroll
        for (int j = 0; j < 16; ++j) acc[i][j] = f32x4_t{0.f, 0.f, 0.f, 0.f};

    #pragma unroll
    for (int kk = 0; kk < 8; ++kk) {
        const int cur = kk % 3;
        if (kk < 7) {                     // W(k+1) into Bs[(k+1)%3]
            const int nxt = (kk + 1) % 3;
            const int k0n = (kk + 1) * 32;
            #pragma unroll
            for (int i = 0; i < 4; ++i) {
                const int seg = wave * 4 + i;
                const int tt = seg >> 1, oh = (seg & 1) * 16;
                gld_lds16((char*)Bs[nxt] + seg * 1024 + lane * 16,
                          gB + (size_t)(tt * 64 + oh + r16) * 1024 + k0n + gsw * 8);
            }
        }
        // A fragments in registers (log2 domain, packed bf16)
        uint4 afr0, afr1;
        {
            const int mbase = kk * 32 + quad * 8;
            float e0[8], e1[8];
            #pragma unroll
            for (int j = 0; j < 8; ++j) {
                const float4 m4 = mp[mbase + j];
                e0[j] = __builtin_amdgcn_exp2f(rh0 + m4.w + rx0 * m4.x
                                               + ry0 * m4.y + rz0 * m4.z);
                e1[j] = __builtin_amdgcn_exp2f(rh1 + m4.w + rx1 * m4.x
                                               + ry1 * m4.y + rz1 * m4.z);
            }
            afr0.x = pkbf(e0[0], e0[1]); afr0.y = pkbf(e0[2], e0[3]);
            afr0.z = pkbf(e0[4], e0[5]); afr0.w = pkbf(e0[6], e0[7]);
            afr1.x = pkbf(e1[0], e1[1]); afr1.y = pkbf(e1[2], e1[3]);
            afr1.z = pkbf(e1[4], e1[5]); afr1.w = pkbf(e1[6], e1[7]);
        }
        // counted drain: wait only W(k)'s 4 (oldest); W(k+1) stays in flight.
        if (kk < 7) asm volatile("s_waitcnt vmcnt(4)" ::: "memory");
        else        asm volatile("s_waitcnt vmcnt(0)" ::: "memory");
        __builtin_amdgcn_s_barrier();
        #pragma unroll
        for (int j = 0; j < 16; ++j) {    // one B-frag live at a time
            uint4 bfr = *(const uint4*)((const char*)Bs[cur] + (j * 16 + fr) * 64 + swoff);
            acc[0][j] = __builtin_amdgcn_mfma_f32_16x16x32_bf16(
                __builtin_bit_cast(bf16x8_t, afr0),
                __builtin_bit_cast(bf16x8_t, bfr), acc[0][j], 0, 0, 0);
            acc[1][j] = __builtin_amdgcn_mfma_f32_16x16x32_bf16(
                __builtin_bit_cast(bf16x8_t, afr1),
                __builtin_bit_cast(bf16x8_t, bfr), acc[1][j], 0, 0, 0);
        }
    }

    // epilogue: res[row][o] = sum_t escT[t][row] * acc — float4 escT reads.
    // frag j covers t = j>>1, channel = ogp*32 + (j&1)*16 + fr.
    const int oo = lane & 15;
    unsigned short* dst = He2 + (size_t)kh * 524288
                              + (size_t)(b * 1024 + n0) * 64 + ogp * 32;
    #pragma unroll
    for (int i = 0; i < 2; ++i) {
        const int rb = row_base + i * 16 + quad * 4;
        float s0[4] = {0.f, 0.f, 0.f, 0.f}, s1[4] = {0.f, 0.f, 0.f, 0.f};
        #pragma unroll
        for (int t = 0; t < 8; ++t) {
            const float4 ev = *(const float4*)&escT[t * 128 + rb];
            s0[0] += ev.x * acc[i][2 * t][0]; s1[0] += ev.x * acc[i][2 * t + 1][0];
            s0[1] += ev.y * acc[i][2 * t][1]; s1[1] += ev.y * acc[i][2 * t + 1][1];
            s0[2] += ev.z * acc[i][2 * t][2]; s1[2] += ev.z * acc[i][2 * t + 1][2];
            s0[3] += ev.w * acc[i][2 * t][3]; s1[3] += ev.w * acc[i][2 * t + 1][3];
        }
        #pragma unroll
        for (int r = 0; r < 4; ++r) {
            dst[(size_t)(rb + r) * 64 + oo] = f2bf(s0[r]);
            dst[(size_t)(rb + r) * 64 + 16 + oo] = f2bf(s1[r]);
        }
    }
}

// K4: out = sum of 4 bf16 He2 partials; fused BN sum/sumsq.
// XCD-matched remap: data-b == blockIdx&7 == XCD (same swizzle as producers).
__global__ __launch_bounds__(256) void k_fin(const unsigned short* __restrict__ He2,
                                             float* __restrict__ out,
                                             float* __restrict__ bns) {
    __shared__ float s1[16][64], s2[16][64];
    const int tid = threadIdx.x;
    const int vb = ((blockIdx.x & 7) << 5) | (blockIdx.x >> 3);  // bijective
    float a0 = 0.f, a1 = 0.f, a2 = 0.f, a3 = 0.f;
    float q0 = 0.f, q1 = 0.f, q2 = 0.f, q3 = 0.f;
    #pragma unroll
    for (int it = 0; it < 2; ++it) {
        const size_t idx = (size_t)vb * 512 + it * 256 + tid;    // ushort4 group
        float4 s = make_float4(0.f, 0.f, 0.f, 0.f);
        #pragma unroll
        for (int p = 0; p < 4; ++p) {
            ushort4 u = *(const ushort4*)(He2 + (size_t)p * 524288 + idx * 4);
            s.x += bf2f(u.x); s.y += bf2f(u.y); s.z += bf2f(u.z); s.w += bf2f(u.w);
        }
        ((float4*)out)[idx] = s;
        a0 += s.x; a1 += s.y; a2 += s.z; a3 += s.w;
        q0 += s.x * s.x; q1 += s.y * s.y; q2 += s.z * s.z; q3 += s.w * s.w;
    }
    const int g = tid >> 4, o4 = (tid & 15) * 4;
    *(float4*)&s1[g][o4] = make_float4(a0, a1, a2, a3);
    *(float4*)&s2[g][o4] = make_float4(q0, q1, q2, q3);
    __syncthreads();
    if (tid < 64) {
        float sa = 0.f, sb = 0.f;
        #pragma unroll
        for (int r = 0; r < 16; ++r) { sa += s1[r][tid]; sb += s2[r][tid]; }
        atomicAdd(&bns[tid], sa);
        atomicAdd(&bns[64 + tid], sb);
    }
}

// K5: in-place BN (training stats) + ReLU. XCD-matched remap like k_fin.
__global__ __launch_bounds__(256) void k_bn(float* __restrict__ out,
                                            const float* __restrict__ bns,
                                            const float* __restrict__ gamma,
                                            const float* __restrict__ beta) {
    const int vb = ((blockIdx.x & 7) << 6) | (blockIdx.x >> 3);  // bijective
    const int i = vb * 256 + threadIdx.x;
    const int o4 = (i & 15) * 4;
    float4 x = ((float4*)out)[i];
    const float4 s  = *(const float4*)&bns[o4];
    const float4 s2 = *(const float4*)&bns[64 + o4];
    const float4 gm = *(const float4*)&gamma[o4];
    const float4 bt = *(const float4*)&beta[o4];
    const float invn = 1.f / 8192.f;
    float m, v, w;
    m = s.x * invn; v = s2.x * invn - m * m; w = __frsqrt_rn(v + BN_EPS) * gm.x;
    x.x = fmaxf((x.x - m) * w + bt.x, 0.f);
    m = s.y * invn; v = s2.y * invn - m * m; w = __frsqrt_rn(v + BN_EPS) * gm.y;
    x.y = fmaxf((x.y - m) * w + bt.y, 0.f);
    m = s.z * invn; v = s2.z * invn - m * m; w = __frsqrt_rn(v + BN_EPS) * gm.z;
    x.z = fmaxf((x.z - m) * w + bt.z, 0.f);
    m = s.w * invn; v = s2.w * invn - m * m; w = __frsqrt_rn(v + BN_EPS) * gm.w;
    x.w = fmaxf((x.w - m) * w + bt.w, 0.f);
    ((float4*)out)[i] = x;
}

extern "C" void kernel_launch(void* const* d_in, const int* in_sizes, int n_in,
                              void* d_out, int out_size, void* d_ws, size_t ws_size,
                              hipStream_t stream) {
    const float* points = (const float*)d_in[0];
    const float* trans  = (const float*)d_in[1];
    const float* funcs  = (const float*)d_in[2];
    const float* ktens  = (const float*)d_in[3];
    const float* gamma  = (const float*)d_in[4];
    const float* beta   = (const float*)d_in[5];
    float* out = (float*)d_out;

    float* ws      = (float*)d_ws;
    float* escale  = ws;                    // 65536 f
    float* bns     = escale + 65536;        // 128 f
    float* rowsum  = bns + 128;             // 8192 f
    unsigned short* He2   = (unsigned short*)(rowsum + 8192);   // 2097152 us (4 MB)
    unsigned short* bmatT = He2 + 2097152;                      // 4194304 us (8 MB)

    k_gp<<<768, 256, 0, stream>>>(points, trans, funcs, ktens,
                                  rowsum, bmatT, escale, bns);
    k_gemm<<<512, 256, 0, stream>>>(points, bmatT, escale, rowsum, He2);
    k_fin<<<256, 256, 0, stream>>>(He2, out, bns);
    k_bn<<<512, 256, 0, stream>>>(out, bns, gamma, beta);
}